// Round 1
// baseline (298.945 us; speedup 1.0000x reference)
//
#include <hip/hip_runtime.h>

// DirectNormLoss: B=16384 rows, D=2048 features, 1000 classes.
// loss = mean_i [ 1 - <s_i, c_i> / (||c_i|| * max(||s_i||, ||t_i||)) ]
// Memory-bound: 2x128MiB (s,t) from HBM + 8MB T_EMB (LLC-resident).

#define NROWS 16384
#define DDIM  2048
#define BLK   256

__global__ __launch_bounds__(BLK) void dnl_row_kernel(
    const float* __restrict__ s_emb,
    const float* __restrict__ t_emb,
    const float* __restrict__ T_EMB,
    const int*   __restrict__ labels,
    float*       __restrict__ partial)   // [NROWS] per-row contributions
{
    const int row = blockIdx.x;
    const int tid = threadIdx.x;
    const int label = labels[row];

    const float4* s4 = (const float4*)(s_emb + (size_t)row   * DDIM);
    const float4* t4 = (const float4*)(t_emb + (size_t)row   * DDIM);
    const float4* c4 = (const float4*)(T_EMB + (size_t)label * DDIM);

    float ss = 0.f, tt = 0.f, sc = 0.f, cc = 0.f;
    // DDIM/4 = 512 float4 per row; 256 threads -> 2 iterations.
    #pragma unroll
    for (int it = 0; it < 2; ++it) {
        const int k = tid + it * BLK;
        const float4 s = s4[k];
        const float4 t = t4[k];
        const float4 c = c4[k];
        ss += s.x*s.x + s.y*s.y + s.z*s.z + s.w*s.w;
        tt += t.x*t.x + t.y*t.y + t.z*t.z + t.w*t.w;
        sc += s.x*c.x + s.y*c.y + s.z*c.z + s.w*c.w;
        cc += c.x*c.x + c.y*c.y + c.z*c.z + c.w*c.w;
    }

    // wave-64 butterfly reduce (4 values)
    #pragma unroll
    for (int off = 32; off > 0; off >>= 1) {
        ss += __shfl_down(ss, off, 64);
        tt += __shfl_down(tt, off, 64);
        sc += __shfl_down(sc, off, 64);
        cc += __shfl_down(cc, off, 64);
    }

    __shared__ float red[4][4];  // [wave][value]
    const int wave = tid >> 6;
    const int lane = tid & 63;
    if (lane == 0) {
        red[wave][0] = ss; red[wave][1] = tt;
        red[wave][2] = sc; red[wave][3] = cc;
    }
    __syncthreads();

    if (tid == 0) {
        float SS = 0.f, TT = 0.f, SC = 0.f, CC = 0.f;
        #pragma unroll
        for (int w = 0; w < 4; ++w) {
            SS += red[w][0]; TT += red[w][1];
            SC += red[w][2]; CC += red[w][3];
        }
        const float max_norm = fmaxf(sqrtf(SS), sqrtf(TT));
        partial[row] = 1.0f - SC / (sqrtf(CC) * max_norm);
    }
}

// Atomic-fallback variant (only used if ws_size < NROWS*4; adds scaled
// contribution directly to out[0], which must be zeroed first).
__global__ __launch_bounds__(BLK) void dnl_row_kernel_atomic(
    const float* __restrict__ s_emb,
    const float* __restrict__ t_emb,
    const float* __restrict__ T_EMB,
    const int*   __restrict__ labels,
    float*       __restrict__ out)
{
    const int row = blockIdx.x;
    const int tid = threadIdx.x;
    const int label = labels[row];

    const float4* s4 = (const float4*)(s_emb + (size_t)row   * DDIM);
    const float4* t4 = (const float4*)(t_emb + (size_t)row   * DDIM);
    const float4* c4 = (const float4*)(T_EMB + (size_t)label * DDIM);

    float ss = 0.f, tt = 0.f, sc = 0.f, cc = 0.f;
    #pragma unroll
    for (int it = 0; it < 2; ++it) {
        const int k = tid + it * BLK;
        const float4 s = s4[k];
        const float4 t = t4[k];
        const float4 c = c4[k];
        ss += s.x*s.x + s.y*s.y + s.z*s.z + s.w*s.w;
        tt += t.x*t.x + t.y*t.y + t.z*t.z + t.w*t.w;
        sc += s.x*c.x + s.y*c.y + s.z*c.z + s.w*c.w;
        cc += c.x*c.x + c.y*c.y + c.z*c.z + c.w*c.w;
    }
    #pragma unroll
    for (int off = 32; off > 0; off >>= 1) {
        ss += __shfl_down(ss, off, 64);
        tt += __shfl_down(tt, off, 64);
        sc += __shfl_down(sc, off, 64);
        cc += __shfl_down(cc, off, 64);
    }
    __shared__ float red[4][4];
    const int wave = tid >> 6;
    const int lane = tid & 63;
    if (lane == 0) {
        red[wave][0] = ss; red[wave][1] = tt;
        red[wave][2] = sc; red[wave][3] = cc;
    }
    __syncthreads();
    if (tid == 0) {
        float SS = 0.f, TT = 0.f, SC = 0.f, CC = 0.f;
        #pragma unroll
        for (int w = 0; w < 4; ++w) {
            SS += red[w][0]; TT += red[w][1];
            SC += red[w][2]; CC += red[w][3];
        }
        const float max_norm = fmaxf(sqrtf(SS), sqrtf(TT));
        const float contrib = 1.0f - SC / (sqrtf(CC) * max_norm);
        atomicAdd(out, contrib * (1.0f / (float)NROWS));
    }
}

__global__ __launch_bounds__(BLK) void dnl_reduce_kernel(
    const float* __restrict__ partial,
    float*       __restrict__ out)
{
    const int tid = threadIdx.x;
    float sum = 0.f;
    // 16384 / 256 = 64 elements per thread, coalesced stride-256.
    for (int i = tid; i < NROWS; i += BLK) sum += partial[i];

    #pragma unroll
    for (int off = 32; off > 0; off >>= 1)
        sum += __shfl_down(sum, off, 64);

    __shared__ float red[4];
    if ((tid & 63) == 0) red[tid >> 6] = sum;
    __syncthreads();
    if (tid == 0)
        out[0] = (red[0] + red[1] + red[2] + red[3]) * (1.0f / (float)NROWS);
}

extern "C" void kernel_launch(void* const* d_in, const int* in_sizes, int n_in,
                              void* d_out, int out_size, void* d_ws, size_t ws_size,
                              hipStream_t stream) {
    const float* s_emb  = (const float*)d_in[0];
    const float* t_emb  = (const float*)d_in[1];
    const float* T_EMB  = (const float*)d_in[2];
    const int*   labels = (const int*)d_in[3];
    float* out = (float*)d_out;

    if (ws_size >= (size_t)NROWS * sizeof(float)) {
        float* partial = (float*)d_ws;
        dnl_row_kernel<<<NROWS, BLK, 0, stream>>>(s_emb, t_emb, T_EMB, labels, partial);
        dnl_reduce_kernel<<<1, BLK, 0, stream>>>(partial, out);
    } else {
        hipMemsetAsync(d_out, 0, sizeof(float), stream);
        dnl_row_kernel_atomic<<<NROWS, BLK, 0, stream>>>(s_emb, t_emb, T_EMB, labels, out);
    }
}

// Round 2
// 287.915 us; speedup vs baseline: 1.0383x; 1.0383x over previous
//
#include <hip/hip_runtime.h>

// DirectNormLoss: B=16384 rows, D=2048 features, 1000 classes.
// loss = mean_i [ 1 - <s_i, c_i> / (||c_i|| * max(||s_i||, ||t_i||)) ]
// Memory-bound: 2x128MiB (s,t) from HBM + 8MB T_EMB (LLC-resident).
//
// R1: one row per WAVE (8 float4/lane/array = 24 outstanding 16B loads/lane),
// __shfl_xor butterfly reduce (no LDS/barrier), 4 rows per wave accumulated
// locally -> one ws write per wave. Reduce kernel handles 4096 wave sums.

#define NROWS      16384
#define DDIM       2048
#define BLK        256
#define GRID       1024
#define NUM_WAVES  (GRID * (BLK / 64))   // 4096

__global__ __launch_bounds__(BLK) void dnl_main_kernel(
    const float* __restrict__ s_emb,
    const float* __restrict__ t_emb,
    const float* __restrict__ T_EMB,
    const int*   __restrict__ labels,
    float*       __restrict__ wavesum)   // [NUM_WAVES]
{
    const int tid   = threadIdx.x;
    const int lane  = tid & 63;
    const int gwave = blockIdx.x * (BLK / 64) + (tid >> 6);

    float acc = 0.f;
    int next_label = labels[gwave];   // prefetch first label (wave-uniform)

    for (int row = gwave; row < NROWS; row += NUM_WAVES) {
        const int label = next_label;
        const int nrow  = row + NUM_WAVES;
        if (nrow < NROWS) next_label = labels[nrow];  // hide gather dep

        const float4* s4 = (const float4*)(s_emb + (size_t)row   * DDIM);
        const float4* t4 = (const float4*)(t_emb + (size_t)row   * DDIM);
        const float4* c4 = (const float4*)(T_EMB + (size_t)label * DDIM);

        float ss = 0.f, tt = 0.f, sc = 0.f, cc = 0.f;
        // 2048/4 = 512 float4 per row; 64 lanes -> 8 per lane per array.
        #pragma unroll
        for (int j = 0; j < 8; ++j) {
            const int k = lane + j * 64;
            const float4 s = s4[k];
            const float4 t = t4[k];
            const float4 c = c4[k];
            ss += s.x*s.x + s.y*s.y + s.z*s.z + s.w*s.w;
            tt += t.x*t.x + t.y*t.y + t.z*t.z + t.w*t.w;
            sc += s.x*c.x + s.y*c.y + s.z*c.z + s.w*c.w;
            cc += c.x*c.x + c.y*c.y + c.z*c.z + c.w*c.w;
        }

        // wave-64 xor butterfly: every lane ends with the full row sums
        #pragma unroll
        for (int off = 32; off > 0; off >>= 1) {
            ss += __shfl_xor(ss, off, 64);
            tt += __shfl_xor(tt, off, 64);
            sc += __shfl_xor(sc, off, 64);
            cc += __shfl_xor(cc, off, 64);
        }

        const float max_norm = fmaxf(sqrtf(ss), sqrtf(tt));
        acc += 1.0f - sc / (sqrtf(cc) * max_norm);   // redundant on all lanes
    }

    if (lane == 0) wavesum[gwave] = acc;
}

__global__ __launch_bounds__(BLK) void dnl_reduce_kernel(
    const float* __restrict__ wavesum,
    float*       __restrict__ out)
{
    const int tid = threadIdx.x;
    const float4* w4 = (const float4*)wavesum;
    // NUM_WAVES/4 = 1024 float4; 256 threads -> 4 each, coalesced.
    float sum = 0.f;
    #pragma unroll
    for (int j = 0; j < 4; ++j) {
        const float4 v = w4[tid + j * BLK];
        sum += v.x + v.y + v.z + v.w;
    }

    #pragma unroll
    for (int off = 32; off > 0; off >>= 1)
        sum += __shfl_xor(sum, off, 64);

    __shared__ float red[4];
    if ((tid & 63) == 0) red[tid >> 6] = sum;
    __syncthreads();
    if (tid == 0)
        out[0] = (red[0] + red[1] + red[2] + red[3]) * (1.0f / (float)NROWS);
}

// Atomic fallback (only if ws too small; adds scaled contribution to out[0]).
__global__ __launch_bounds__(BLK) void dnl_main_atomic_kernel(
    const float* __restrict__ s_emb,
    const float* __restrict__ t_emb,
    const float* __restrict__ T_EMB,
    const int*   __restrict__ labels,
    float*       __restrict__ out)
{
    const int tid   = threadIdx.x;
    const int lane  = tid & 63;
    const int gwave = blockIdx.x * (BLK / 64) + (tid >> 6);

    float acc = 0.f;
    for (int row = gwave; row < NROWS; row += NUM_WAVES) {
        const int label = labels[row];
        const float4* s4 = (const float4*)(s_emb + (size_t)row   * DDIM);
        const float4* t4 = (const float4*)(t_emb + (size_t)row   * DDIM);
        const float4* c4 = (const float4*)(T_EMB + (size_t)label * DDIM);
        float ss = 0.f, tt = 0.f, sc = 0.f, cc = 0.f;
        #pragma unroll
        for (int j = 0; j < 8; ++j) {
            const int k = lane + j * 64;
            const float4 s = s4[k];
            const float4 t = t4[k];
            const float4 c = c4[k];
            ss += s.x*s.x + s.y*s.y + s.z*s.z + s.w*s.w;
            tt += t.x*t.x + t.y*t.y + t.z*t.z + t.w*t.w;
            sc += s.x*c.x + s.y*c.y + s.z*c.z + s.w*c.w;
            cc += c.x*c.x + c.y*c.y + c.z*c.z + c.w*c.w;
        }
        #pragma unroll
        for (int off = 32; off > 0; off >>= 1) {
            ss += __shfl_xor(ss, off, 64);
            tt += __shfl_xor(tt, off, 64);
            sc += __shfl_xor(sc, off, 64);
            cc += __shfl_xor(cc, off, 64);
        }
        const float max_norm = fmaxf(sqrtf(ss), sqrtf(tt));
        acc += 1.0f - sc / (sqrtf(cc) * max_norm);
    }
    if (lane == 0) atomicAdd(out, acc * (1.0f / (float)NROWS));
}

extern "C" void kernel_launch(void* const* d_in, const int* in_sizes, int n_in,
                              void* d_out, int out_size, void* d_ws, size_t ws_size,
                              hipStream_t stream) {
    const float* s_emb  = (const float*)d_in[0];
    const float* t_emb  = (const float*)d_in[1];
    const float* T_EMB  = (const float*)d_in[2];
    const int*   labels = (const int*)d_in[3];
    float* out = (float*)d_out;

    if (ws_size >= (size_t)NUM_WAVES * sizeof(float)) {
        float* wavesum = (float*)d_ws;
        dnl_main_kernel<<<GRID, BLK, 0, stream>>>(s_emb, t_emb, T_EMB, labels, wavesum);
        dnl_reduce_kernel<<<1, BLK, 0, stream>>>(wavesum, out);
    } else {
        hipMemsetAsync(d_out, 0, sizeof(float), stream);
        dnl_main_atomic_kernel<<<GRID, BLK, 0, stream>>>(s_emb, t_emb, T_EMB, labels, out);
    }
}

// Round 3
// 287.665 us; speedup vs baseline: 1.0392x; 1.0009x over previous
//
#include <hip/hip_runtime.h>

// DirectNormLoss: B=16384 rows, D=2048 features, 1000 classes.
// loss = mean_i [ 1 - <s_i, c_i> / (||c_i|| * max(||s_i||, ||t_i||)) ]
//
// R2 theory: R0/R1 were stuck at 1.8 TB/s because default launch bounds
// capped VGPRs (28/52), forcing the compiler to consume loads in batches of
// ~3-6 with waitcnt between -> ~5 KB in flight per wave. This round:
// __launch_bounds__(256,2) (<=256 VGPR), one row per wave, ALL 24 float4
// loads issued up-front into registers, 16384 waves for continuous refill.

#define NROWS  16384
#define DDIM   2048
#define BLK    256
#define WPB    (BLK / 64)          // waves per block = 4
#define GRID   (NROWS / WPB)       // 4096 blocks -> 16384 waves, 1 row each

__global__ __launch_bounds__(BLK, 2) void dnl_main_kernel(
    const float* __restrict__ s_emb,
    const float* __restrict__ t_emb,
    const float* __restrict__ T_EMB,
    const int*   __restrict__ labels,
    float*       __restrict__ partial)   // [NROWS]
{
    const int tid  = threadIdx.x;
    const int lane = tid & 63;
    const int row  = blockIdx.x * WPB + (tid >> 6);   // wave-uniform

    const int label = labels[row];                    // scalar load

    const float4* s4 = (const float4*)(s_emb + (size_t)row   * DDIM);
    const float4* t4 = (const float4*)(t_emb + (size_t)row   * DDIM);
    const float4* c4 = (const float4*)(T_EMB + (size_t)label * DDIM);

    // ---- load phase: 24 independent float4 loads, all in flight ----
    float4 sv[8], tv[8], cv[8];
    #pragma unroll
    for (int j = 0; j < 8; ++j) sv[j] = s4[lane + j * 64];
    #pragma unroll
    for (int j = 0; j < 8; ++j) tv[j] = t4[lane + j * 64];
    #pragma unroll
    for (int j = 0; j < 8; ++j) cv[j] = c4[lane + j * 64];

    // ---- accumulate phase ----
    float ss = 0.f, tt = 0.f, sc = 0.f, cc = 0.f;
    #pragma unroll
    for (int j = 0; j < 8; ++j) {
        const float4 s = sv[j], t = tv[j], c = cv[j];
        ss += s.x*s.x + s.y*s.y + s.z*s.z + s.w*s.w;
        tt += t.x*t.x + t.y*t.y + t.z*t.z + t.w*t.w;
        sc += s.x*c.x + s.y*c.y + s.z*c.z + s.w*c.w;
        cc += c.x*c.x + c.y*c.y + c.z*c.z + c.w*c.w;
    }

    // ---- wave-64 xor butterfly: all lanes end with full row sums ----
    #pragma unroll
    for (int off = 32; off > 0; off >>= 1) {
        ss += __shfl_xor(ss, off, 64);
        tt += __shfl_xor(tt, off, 64);
        sc += __shfl_xor(sc, off, 64);
        cc += __shfl_xor(cc, off, 64);
    }

    if (lane == 0) {
        const float max_norm = fmaxf(sqrtf(ss), sqrtf(tt));
        partial[row] = 1.0f - sc / (sqrtf(cc) * max_norm);
    }
}

__global__ __launch_bounds__(BLK) void dnl_reduce_kernel(
    const float* __restrict__ partial,
    float*       __restrict__ out)
{
    const int tid = threadIdx.x;
    const float4* p4 = (const float4*)partial;
    // NROWS/4 = 4096 float4; 256 threads -> 16 each, coalesced.
    float sum = 0.f;
    #pragma unroll
    for (int j = 0; j < 16; ++j) {
        const float4 v = p4[tid + j * BLK];
        sum += v.x + v.y + v.z + v.w;
    }

    #pragma unroll
    for (int off = 32; off > 0; off >>= 1)
        sum += __shfl_xor(sum, off, 64);

    __shared__ float red[4];
    if ((tid & 63) == 0) red[tid >> 6] = sum;
    __syncthreads();
    if (tid == 0)
        out[0] = (red[0] + red[1] + red[2] + red[3]) * (1.0f / (float)NROWS);
}

// Atomic fallback (only if ws too small).
__global__ __launch_bounds__(BLK, 2) void dnl_main_atomic_kernel(
    const float* __restrict__ s_emb,
    const float* __restrict__ t_emb,
    const float* __restrict__ T_EMB,
    const int*   __restrict__ labels,
    float*       __restrict__ out)
{
    const int tid  = threadIdx.x;
    const int lane = tid & 63;
    const int row  = blockIdx.x * WPB + (tid >> 6);
    const int label = labels[row];

    const float4* s4 = (const float4*)(s_emb + (size_t)row   * DDIM);
    const float4* t4 = (const float4*)(t_emb + (size_t)row   * DDIM);
    const float4* c4 = (const float4*)(T_EMB + (size_t)label * DDIM);

    float4 sv[8], tv[8], cv[8];
    #pragma unroll
    for (int j = 0; j < 8; ++j) sv[j] = s4[lane + j * 64];
    #pragma unroll
    for (int j = 0; j < 8; ++j) tv[j] = t4[lane + j * 64];
    #pragma unroll
    for (int j = 0; j < 8; ++j) cv[j] = c4[lane + j * 64];

    float ss = 0.f, tt = 0.f, sc = 0.f, cc = 0.f;
    #pragma unroll
    for (int j = 0; j < 8; ++j) {
        const float4 s = sv[j], t = tv[j], c = cv[j];
        ss += s.x*s.x + s.y*s.y + s.z*s.z + s.w*s.w;
        tt += t.x*t.x + t.y*t.y + t.z*t.z + t.w*t.w;
        sc += s.x*c.x + s.y*c.y + s.z*c.z + s.w*c.w;
        cc += c.x*c.x + c.y*c.y + c.z*c.z + c.w*c.w;
    }
    #pragma unroll
    for (int off = 32; off > 0; off >>= 1) {
        ss += __shfl_xor(ss, off, 64);
        tt += __shfl_xor(tt, off, 64);
        sc += __shfl_xor(sc, off, 64);
        cc += __shfl_xor(cc, off, 64);
    }
    if (lane == 0) {
        const float max_norm = fmaxf(sqrtf(ss), sqrtf(tt));
        atomicAdd(out, (1.0f - sc / (sqrtf(cc) * max_norm)) * (1.0f / (float)NROWS));
    }
}

extern "C" void kernel_launch(void* const* d_in, const int* in_sizes, int n_in,
                              void* d_out, int out_size, void* d_ws, size_t ws_size,
                              hipStream_t stream) {
    const float* s_emb  = (const float*)d_in[0];
    const float* t_emb  = (const float*)d_in[1];
    const float* T_EMB  = (const float*)d_in[2];
    const int*   labels = (const int*)d_in[3];
    float* out = (float*)d_out;

    if (ws_size >= (size_t)NROWS * sizeof(float)) {
        float* partial = (float*)d_ws;
        dnl_main_kernel<<<GRID, BLK, 0, stream>>>(s_emb, t_emb, T_EMB, labels, partial);
        dnl_reduce_kernel<<<1, BLK, 0, stream>>>(partial, out);
    } else {
        hipMemsetAsync(d_out, 0, sizeof(float), stream);
        dnl_main_atomic_kernel<<<GRID, BLK, 0, stream>>>(s_emb, t_emb, T_EMB, labels, out);
    }
}